// Round 3
// baseline (4180.313 us; speedup 1.0000x reference)
//
#include <hip/hip_runtime.h>
#include <hip/hip_bf16.h>

// LSTM decoder: L=512, B=64, A=256, I=256, H=512, 4H=2048.
// Persistent kernel: 64 WGs, each owns 8 hidden units (32 gate rows).
// R3: swapped MFMA (A=weights, D rows=gate rows permuted so r4=gate) ->
// cell update in accumulator regs, no gbuf. Per-WG flag ring + wave-parallel
// poll. h exchanged via relaxed agent-scope atomics (no fences, no L2 inv).

#define NWG     64
#define LSTEPS  512
#define BATCH   64
#define HDIM    512
#define ADIM    256
#define GDIM    2048
#define KTOT    768
#define LBH     (LSTEPS*BATCH*HDIM)
#define HWORDS  (BATCH*256)          // u32 words per h buffer

typedef __attribute__((ext_vector_type(4))) float f32x4;
typedef __attribute__((ext_vector_type(8))) short s16x8;
typedef unsigned long long u64t;

__device__ __forceinline__ unsigned short f2bf(float f){
  unsigned u = __builtin_bit_cast(unsigned, f);
  u = (u + 0x7fffu + ((u >> 16) & 1u)) >> 16;
  return (unsigned short)u;
}
__device__ __forceinline__ float sigm(float x){ return 1.f / (1.f + __expf(-x)); }
__device__ __forceinline__ float ftanh(float x){ return 1.f - 2.f / (__expf(2.f*x) + 1.f); }

// ---------------- precompute kernels ----------------

__global__ void cvt_act(const float* __restrict__ in, unsigned short* __restrict__ ob, int n8){
  int i = blockIdx.x * blockDim.x + threadIdx.x;
  if (i >= n8) return;
  const float4* p = (const float4*)in + (size_t)i * 2;
  float4 a = p[0], b = p[1];
  int4 o;
  o.x = (int)((unsigned)f2bf(a.x) | ((unsigned)f2bf(a.y) << 16));
  o.y = (int)((unsigned)f2bf(a.z) | ((unsigned)f2bf(a.w) << 16));
  o.z = (int)((unsigned)f2bf(b.x) | ((unsigned)f2bf(b.y) << 16));
  o.w = (int)((unsigned)f2bf(b.z) | ((unsigned)f2bf(b.w) << 16));
  ((int4*)ob)[i] = o;
}

__global__ void static_gates_k(const float* __restrict__ inp, const float* __restrict__ Wih,
                               const float* __restrict__ bih, const float* __restrict__ bhh,
                               float* __restrict__ statg){
  int g = blockIdx.x;
  int b = threadIdx.x;
  const float4* w = (const float4*)(Wih + (size_t)g * 512);
  const float4* x = (const float4*)(inp + (size_t)b * 256);
  float acc = 0.f;
#pragma unroll 8
  for (int i = 0; i < 64; ++i){
    float4 wv = w[i], xv = x[i];
    acc += wv.x*xv.x + wv.y*xv.y + wv.z*xv.z + wv.w*xv.w;
  }
  statg[b*GDIM + g] = acc + bih[g] + bhh[g];
}

__global__ void init_h(const float* __restrict__ h0, unsigned int* __restrict__ hbuf32){
  int i = blockIdx.x * blockDim.x + threadIdx.x;
  if (i < HWORDS){
    unsigned lo = f2bf(h0[2*i]), hi = f2bf(h0[2*i+1]);
    hbuf32[HWORDS + i] = lo | (hi << 16);
  }
}

// ---------------- persistent LSTM kernel ----------------

__global__ __launch_bounds__(256, 1) void lstm_persistent(
    const unsigned short* __restrict__ act_bf,   // [L][B][A] bf16
    const float*          __restrict__ statg,    // [B][4H]
    const float*          __restrict__ Whh,      // [4H][H]
    const float*          __restrict__ Wih,      // [4H][I+A]
    const float*          __restrict__ c0,       // [B][H]
    float*                __restrict__ out,      // hs, h_n, c_n
    unsigned int*         __restrict__ hbuf32,   // [2][B][256] packed bf16x2
    unsigned int*         __restrict__ done)     // [8][64] flag ring
{
  __shared__ short Albuf[64 * KTOT];   // [batch 64][K 768] bf16, XOR-swizzled
  __shared__ float hb[64 * 9];         // h bounce, padded stride 9

  const int tid   = threadIdx.x;
  const int wgk   = blockIdx.x;        // owns hidden units [8*wgk, 8*wgk+8)
  const int lane  = tid & 63;
  const int wid   = tid >> 6;
  const int m     = wid & 1;           // gate-row 16-tile
  const int npair = wid >> 1;          // batch 32-group (2 n-tiles)
  const int kgrp  = (lane >> 4) * 8;

  // ---- A-frags (weights) in regs. D-row permutation: row_in_tile = u_off*4+g4,
  //      tile m covers units m*4+u_off  =>  grow = g4*512 + wgk*8 + m*4 + u_off.
  const int rit  = lane & 15;
  const int grow = (rit & 3)*512 + wgk*8 + m*4 + (rit >> 2);
  s16x8 aw[24];
#pragma unroll
  for (int kk = 0; kk < 16; ++kk){                 // K 0..511 : W_hh
    s16x8 v;
    const int kb = kk*32 + kgrp;
#pragma unroll
    for (int e = 0; e < 8; ++e)
      v[e] = (short)f2bf(Whh[(size_t)grow*512 + kb + e]);
    aw[kk] = v;
  }
#pragma unroll
  for (int kk = 16; kk < 24; ++kk){                // K 512..767 : W_a (cols 256..511)
    s16x8 v;
    const int kb = kk*32 + kgrp;
#pragma unroll
    for (int e = 0; e < 8; ++e)
      v[e] = (short)f2bf(Wih[(size_t)grow*512 + (kb - 256) + e]);
    aw[kk] = v;
  }

  // ---- cell-state mapping (C/D layout: col=lane&15 -> batch, row=(lane>>4)*4+r4) ----
  const int bA = (npair*2)*16 + (lane & 15);       // batch for n-tile 0
  const int bB = bA + 16;                          // batch for n-tile 1
  const int j  = wgk*8 + m*4 + (lane >> 4);        // hidden unit
  const int uloc = m*4 + (lane >> 4);              // unit index within WG (0..7)
  float stat[2][4], cr[2];
#pragma unroll
  for (int g4 = 0; g4 < 4; ++g4){
    stat[0][g4] = statg[bA*GDIM + g4*512 + j];
    stat[1][g4] = statg[bB*GDIM + g4*512 + j];
  }
  cr[0] = c0[bA*HDIM + j];
  cr[1] = c0[bB*HDIM + j];

  // LDS row bases for B-frag reads
  const int r0  = bA;                  // row = batch
  const int sw0 = (r0 & 7) * 8;        // (r0&7)==(r1&7)

  // ---- prestage act for t=0 ----
  {
    const unsigned short* asrc = act_bf;
#pragma unroll
    for (int it = 0; it < 8; ++it){
      const int idx = it*256 + tid;
      const int r = idx >> 5, ch = idx & 31;
      int4 v = *(const int4*)(asrc + r*ADIM + ch*8);
      *(int4*)(&Albuf[r*KTOT + 512 + ((ch ^ (r & 7)) * 8)]) = v;
    }
  }

  for (int t = 0; t < LSTEPS; ++t){
    // ---- wait for h_{t-1}: wave-parallel poll of 64 per-WG flags ----
    if (t > 0){
      unsigned v;
      const unsigned* fl = &done[((t-1) & 7)*64 + lane];
      do {
        v = __hip_atomic_load(fl, __ATOMIC_RELAXED, __HIP_MEMORY_SCOPE_AGENT);
      } while (!__all(v == (unsigned)t));
    }
    // ---- stage h (coherent u64 atomic loads -> LDS, swizzled) ----
    {
      const u64t* hsrc = (const u64t*)(hbuf32 + ((t+1) & 1) * HWORDS);
#pragma unroll
      for (int it = 0; it < 16; ++it){
        const int idx = it*256 + tid;
        const int r = idx >> 6, ch = idx & 63;
        u64t a = __hip_atomic_load(hsrc + r*128 + ch*2,     __ATOMIC_RELAXED, __HIP_MEMORY_SCOPE_AGENT);
        u64t b = __hip_atomic_load(hsrc + r*128 + ch*2 + 1, __ATOMIC_RELAXED, __HIP_MEMORY_SCOPE_AGENT);
        int4 v;
        v.x = (int)(unsigned)(a & 0xffffffffull);
        v.y = (int)(unsigned)(a >> 32);
        v.z = (int)(unsigned)(b & 0xffffffffull);
        v.w = (int)(unsigned)(b >> 32);
        *(int4*)(&Albuf[r*KTOT + ((ch ^ (r & 7)) * 8)]) = v;
      }
    }
    __syncthreads();   // B1: tile staged

    // ---- MFMA: D[32 gate rows][64 batch], wave = 1 m-tile x 2 n-tiles ----
    f32x4 acc0 = {0.f,0.f,0.f,0.f}, acc1 = {0.f,0.f,0.f,0.f};
    {
      const short* arow0 = &Albuf[r0 * KTOT];
      const short* arow1 = &Albuf[(r0+16) * KTOT];
#pragma unroll
      for (int kk = 0; kk < 24; ++kk){
        const int col = (kk*32 + kgrp) ^ sw0;
        s16x8 b0 = *(const s16x8*)(arow0 + col);
        s16x8 b1 = *(const s16x8*)(arow1 + col);
        acc0 = __builtin_amdgcn_mfma_f32_16x16x32_bf16(aw[kk], b0, acc0, 0, 0, 0);
        acc1 = __builtin_amdgcn_mfma_f32_16x16x32_bf16(aw[kk], b1, acc1, 0, 0, 0);
      }
    }

    // ---- cell update in regs (r4 = gate index thanks to row permutation) ----
    float hv[2];
    {
      float iv = sigm(acc0[0] + stat[0][0]);
      float fv = sigm(acc0[1] + stat[0][1]);
      float gv = ftanh(acc0[2] + stat[0][2]);
      float ov = sigm(acc0[3] + stat[0][3]);
      float c = fv * cr[0] + iv * gv;
      cr[0] = c; hv[0] = ov * ftanh(c);
      iv = sigm(acc1[0] + stat[1][0]);
      fv = sigm(acc1[1] + stat[1][1]);
      gv = ftanh(acc1[2] + stat[1][2]);
      ov = sigm(acc1[3] + stat[1][3]);
      c = fv * cr[1] + iv * gv;
      cr[1] = c; hv[1] = ov * ftanh(c);
    }
    hb[bA*9 + uloc] = hv[0];
    hb[bB*9 + uloc] = hv[1];
    __syncthreads();   // B2: hb complete

    // ---- publish (wave 0): pack row -> 16B, coherent stores; then flag ----
    if (tid < 64){
      const int b = tid;
      float h0 = hb[b*9+0], h1 = hb[b*9+1], h2 = hb[b*9+2], h3 = hb[b*9+3];
      float h4 = hb[b*9+4], h5 = hb[b*9+5], h6 = hb[b*9+6], h7 = hb[b*9+7];
      unsigned w0 = (unsigned)f2bf(h0) | ((unsigned)f2bf(h1) << 16);
      unsigned w1 = (unsigned)f2bf(h2) | ((unsigned)f2bf(h3) << 16);
      unsigned w2 = (unsigned)f2bf(h4) | ((unsigned)f2bf(h5) << 16);
      unsigned w3 = (unsigned)f2bf(h6) | ((unsigned)f2bf(h7) << 16);
      u64t lo = (u64t)w0 | ((u64t)w1 << 32);
      u64t hi = (u64t)w2 | ((u64t)w3 << 32);
      u64t* dst = (u64t*)(hbuf32 + (t & 1)*HWORDS + b*256 + wgk*4);
      __hip_atomic_store(dst,     lo, __ATOMIC_RELAXED, __HIP_MEMORY_SCOPE_AGENT);
      __hip_atomic_store(dst + 1, hi, __ATOMIC_RELAXED, __HIP_MEMORY_SCOPE_AGENT);
    }
    asm volatile("s_waitcnt vmcnt(0)" ::: "memory");
    if (tid == 0)
      __hip_atomic_store(&done[(t & 7)*64 + wgk], (unsigned)(t+1),
                         __ATOMIC_RELAXED, __HIP_MEMORY_SCOPE_AGENT);

    // ---- off-critical-path: hs output, finals, next act prestage ----
    {
      const int b = tid >> 2, q = (tid & 3)*2;
      float2 h2o; h2o.x = hb[b*9+q]; h2o.y = hb[b*9+q+1];
      *(float2*)&out[((size_t)t*BATCH + b)*HDIM + wgk*8 + q] = h2o;
    }
    if (t == LSTEPS-1){
      out[LBH + bA*HDIM + j] = hv[0];
      out[LBH + bB*HDIM + j] = hv[1];
      out[LBH + BATCH*HDIM + bA*HDIM + j] = cr[0];
      out[LBH + BATCH*HDIM + bB*HDIM + j] = cr[1];
    } else {
      const unsigned short* asrc = act_bf + (size_t)(t+1) * (BATCH*ADIM);
#pragma unroll
      for (int it = 0; it < 8; ++it){
        const int idx = it*256 + tid;
        const int r = idx >> 5, ch = idx & 31;
        int4 v = *(const int4*)(asrc + r*ADIM + ch*8);
        *(int4*)(&Albuf[r*KTOT + 512 + ((ch ^ (r & 7)) * 8)]) = v;
      }
    }
    // next-iter h staging writes a different Albuf region; B1 covers the race.
  }
}

// ---------------- launch ----------------

extern "C" void kernel_launch(void* const* d_in, const int* in_sizes, int n_in,
                              void* d_out, int out_size, void* d_ws, size_t ws_size,
                              hipStream_t stream){
  const float* act = (const float*)d_in[0];
  const float* inp = (const float*)d_in[1];
  const float* h0  = (const float*)d_in[2];
  const float* c0  = (const float*)d_in[3];
  const float* Wih = (const float*)d_in[4];
  const float* Whh = (const float*)d_in[5];
  const float* bih = (const float*)d_in[6];
  const float* bhh = (const float*)d_in[7];
  float* out = (float*)d_out;

  char* ws = (char*)d_ws;
  unsigned short* act_bf = (unsigned short*)ws;                          // 16 MiB
  unsigned int*   hbuf32 = (unsigned int*)(ws + 16777216);               // 128 KiB
  float*          statg  = (float*)(ws + 16777216 + 131072);             // 512 KiB
  unsigned int*   done   = (unsigned int*)(ws + 16777216 + 131072 + 524288); // 2 KiB ring

  hipMemsetAsync(done, 0, 8*64*sizeof(unsigned int), stream);
  cvt_act<<<4096, 256, 0, stream>>>(act, act_bf, (LSTEPS*BATCH*ADIM)/8);
  static_gates_k<<<GDIM, 64, 0, stream>>>(inp, Wih, bih, bhh, statg);
  init_h<<<64, 256, 0, stream>>>(h0, hbuf32);
  lstm_persistent<<<NWG, 256, 0, stream>>>(act_bf, statg, Whh, Wih, c0, out, hbuf32, done);
}